// Round 1
// baseline (98.384 us; speedup 1.0000x reference)
//
#include <hip/hip_runtime.h>
#include <math.h>

// Problem constants (from reference):
//   x:   [B=8, R=100, C=100, T=20] int32
//   emb: [50257, 128] f32
//   W:   [128, 1] f32, b: [1] f32
//   out: [8,100,100] f32 = dot(gelu(mean_t emb[x[t]]), W) + b
constexpr int T_TOK = 20;
constexpr int DIM   = 128;

__global__ __launch_bounds__(256) void gelu_embed_kernel(
    const int* __restrict__ x,
    const float* __restrict__ emb,
    const float* __restrict__ W,
    const float* __restrict__ b,
    float* __restrict__ out,
    int n_out)
{
    // one 64-lane wave per output element; 4 waves per block
    const int wave = (int)((blockIdx.x * blockDim.x + threadIdx.x) >> 6);
    const int lane = (int)(threadIdx.x & 63);
    if (wave >= n_out) return;

    const int* ids = x + (size_t)wave * T_TOK;

    // each lane owns dims [2*lane, 2*lane+1] -> float2 loads, 512B/wave/row
    float2 acc = make_float2(0.f, 0.f);
    #pragma unroll
    for (int t = 0; t < T_TOK; ++t) {
        const int id = ids[t];  // wave-uniform broadcast load
        const float2 v = *reinterpret_cast<const float2*>(
            emb + (size_t)id * DIM + (size_t)(lane * 2));
        acc.x += v.x;
        acc.y += v.y;
    }

    const float inv_t = 1.0f / (float)T_TOK;
    const float ax = acc.x * inv_t;
    const float ay = acc.y * inv_t;

    // exact erf GELU: 0.5*x*(1+erf(x/sqrt(2)))
    const float kInvSqrt2 = 0.70710678118654752440f;
    const float gx = 0.5f * ax * (1.0f + erff(ax * kInvSqrt2));
    const float gy = 0.5f * ay * (1.0f + erff(ay * kInvSqrt2));

    const float2 w = *reinterpret_cast<const float2*>(W + (size_t)(lane * 2));
    float p = gx * w.x + gy * w.y;

    // full-wave (64-lane) reduction
    #pragma unroll
    for (int off = 32; off >= 1; off >>= 1)
        p += __shfl_down(p, off, 64);

    if (lane == 0)
        out[wave] = p + b[0];
}

extern "C" void kernel_launch(void* const* d_in, const int* in_sizes, int n_in,
                              void* d_out, int out_size, void* d_ws, size_t ws_size,
                              hipStream_t stream) {
    const int*   x   = (const int*)d_in[0];
    const float* emb = (const float*)d_in[1];
    const float* W   = (const float*)d_in[2];
    const float* b   = (const float*)d_in[3];
    float* out = (float*)d_out;

    const int n_out = out_size;               // B*R*C = 80000
    const int waves_per_block = 4;            // 256 threads
    const int blocks = (n_out + waves_per_block - 1) / waves_per_block;

    gelu_embed_kernel<<<blocks, 256, 0, stream>>>(x, emb, W, b, out, n_out);
}

// Round 2
// 46.561 us; speedup vs baseline: 2.1130x; 2.1130x over previous
//
#include <hip/hip_runtime.h>
#include <hip/hip_bf16.h>
#include <math.h>

// Problem constants (from reference):
//   x:   [B=8, R=100, C=100, T=20] int32   (n_out = 80000 elements, 20 tokens each)
//   emb: [50257, 128] f32
//   W:   [128, 1] f32, b: [1] f32
//   out: [8,100,100] f32 = dot(gelu(mean_t emb[x[t]]), W) + b
constexpr int T_TOK  = 20;
constexpr int DIM    = 128;
constexpr int VOCAB  = 50257;
constexpr int NSLICE = 4;      // dim-slices; slice table = 50257*32*2B = 3.2MB < 4MB L2/XCD
constexpr int SDIM   = DIM / NSLICE;  // 32 dims per slice

// ---------------- convert: emb [V][128] f32 -> embt [NSLICE][V][32] bf16 ----------------
__global__ __launch_bounds__(256) void convert_kernel(const float* __restrict__ emb,
                                                      ushort* __restrict__ embt)
{
    const int NWORK = VOCAB * (DIM / 8);           // each work item converts 8 dims
    int i = blockIdx.x * 256 + threadIdx.x;
    if (i >= NWORK) return;
    const int v  = i >> 4;        // vocab row
    const int j  = i & 15;        // which 8-dim chunk (0..15)
    const int s  = j >> 2;        // slice (0..3)
    const int jj = j & 3;         // chunk within slice (0..3)

    const float* src = emb + (size_t)v * DIM + j * 8;
    const float4 a = *reinterpret_cast<const float4*>(src);
    const float4 c = *reinterpret_cast<const float4*>(src + 4);

    auto pack2 = [](float lo, float hi) -> unsigned int {
        unsigned int l = __bfloat16_as_ushort(__float2bfloat16(lo));
        unsigned int h = __bfloat16_as_ushort(__float2bfloat16(hi));
        return l | (h << 16);
    };
    uint4 u;
    u.x = pack2(a.x, a.y);
    u.y = pack2(a.z, a.w);
    u.z = pack2(c.x, c.y);
    u.w = pack2(c.z, c.w);

    ushort* dst = embt + ((size_t)s * VOCAB + v) * SDIM + jj * 8;   // 16B aligned
    *reinterpret_cast<uint4*>(dst) = u;
}

// ---------------- gather: one 4-lane group per (output, slice) ----------------
// block = 256 threads = 4 waves; wave = 16 groups -> 16 outputs; block -> 64 outputs, 1 slice
__global__ __launch_bounds__(256) void gather_kernel(
    const int* __restrict__ x,
    const ushort* __restrict__ embt,
    const float* __restrict__ W,
    float* __restrict__ part,
    int n_out)
{
    const int s     = blockIdx.x & (NSLICE - 1);        // slice -> XCD via %8 round robin
    const int obase = (blockIdx.x >> 2) * 64;
    const int wv    = threadIdx.x >> 6;
    const int lane  = threadIdx.x & 63;
    const int g     = lane >> 2;                        // group within wave (0..15)
    const int j     = lane & 3;                         // lane within group: dims [8j,8j+8)
    const int o     = obase + wv * 16 + g;
    if (o >= n_out) return;

    // load the 20 token ids (80B, 16B-aligned) -> registers
    int ids_r[T_TOK];
    const int4* xp = reinterpret_cast<const int4*>(x + (size_t)o * T_TOK);
    #pragma unroll
    for (int q = 0; q < T_TOK / 4; ++q) {
        int4 t4 = xp[q];
        ids_r[4 * q + 0] = t4.x;
        ids_r[4 * q + 1] = t4.y;
        ids_r[4 * q + 2] = t4.z;
        ids_r[4 * q + 3] = t4.w;
    }

    const ushort* base = embt + (size_t)s * VOCAB * SDIM + j * 8;
    float acc[8] = {0.f, 0.f, 0.f, 0.f, 0.f, 0.f, 0.f, 0.f};

    #pragma unroll
    for (int t = 0; t < T_TOK; ++t) {
        const uint4 u = *reinterpret_cast<const uint4*>(base + (size_t)ids_r[t] * SDIM);
        acc[0] += __uint_as_float(u.x << 16);
        acc[1] += __uint_as_float(u.x & 0xffff0000u);
        acc[2] += __uint_as_float(u.y << 16);
        acc[3] += __uint_as_float(u.y & 0xffff0000u);
        acc[4] += __uint_as_float(u.z << 16);
        acc[5] += __uint_as_float(u.z & 0xffff0000u);
        acc[6] += __uint_as_float(u.w << 16);
        acc[7] += __uint_as_float(u.w & 0xffff0000u);
    }

    const float inv_t = 1.0f / (float)T_TOK;
    const float kInvSqrt2 = 0.70710678118654752440f;
    const float* wp = W + s * SDIM + j * 8;
    float p = 0.f;
    #pragma unroll
    for (int k = 0; k < 8; ++k) {
        const float a  = acc[k] * inv_t;
        const float gl = 0.5f * a * (1.0f + erff(a * kInvSqrt2));
        p += gl * wp[k];
    }

    // reduce within the 4-lane group
    p += __shfl_xor(p, 1, 64);
    p += __shfl_xor(p, 2, 64);
    if (j == 0)
        part[(size_t)s * n_out + o] = p;
}

// ---------------- reduce: out[o] = b + sum_s part[s][o] ----------------
__global__ __launch_bounds__(256) void reduce_kernel(const float* __restrict__ part,
                                                     const float* __restrict__ b,
                                                     float* __restrict__ out,
                                                     int n_out)
{
    int o = blockIdx.x * 256 + threadIdx.x;
    if (o >= n_out) return;
    float v = b[0];
    #pragma unroll
    for (int s = 0; s < NSLICE; ++s)
        v += part[(size_t)s * n_out + o];
    out[o] = v;
}

// ---------------- fallback (round-1 kernel) if ws too small ----------------
__global__ __launch_bounds__(256) void gelu_embed_fallback(
    const int* __restrict__ x, const float* __restrict__ emb,
    const float* __restrict__ W, const float* __restrict__ b,
    float* __restrict__ out, int n_out)
{
    const int wave = (int)((blockIdx.x * blockDim.x + threadIdx.x) >> 6);
    const int lane = (int)(threadIdx.x & 63);
    if (wave >= n_out) return;
    const int* ids = x + (size_t)wave * T_TOK;
    float2 acc = make_float2(0.f, 0.f);
    #pragma unroll
    for (int t = 0; t < T_TOK; ++t) {
        const int id = ids[t];
        const float2 v = *reinterpret_cast<const float2*>(
            emb + (size_t)id * DIM + (size_t)(lane * 2));
        acc.x += v.x; acc.y += v.y;
    }
    const float inv_t = 1.0f / (float)T_TOK;
    const float ax = acc.x * inv_t, ay = acc.y * inv_t;
    const float kInvSqrt2 = 0.70710678118654752440f;
    const float gx = 0.5f * ax * (1.0f + erff(ax * kInvSqrt2));
    const float gy = 0.5f * ay * (1.0f + erff(ay * kInvSqrt2));
    const float2 w = *reinterpret_cast<const float2*>(W + (size_t)(lane * 2));
    float p = gx * w.x + gy * w.y;
    #pragma unroll
    for (int off = 32; off >= 1; off >>= 1) p += __shfl_down(p, off, 64);
    if (lane == 0) out[wave] = p + b[0];
}

extern "C" void kernel_launch(void* const* d_in, const int* in_sizes, int n_in,
                              void* d_out, int out_size, void* d_ws, size_t ws_size,
                              hipStream_t stream) {
    const int*   x   = (const int*)d_in[0];
    const float* emb = (const float*)d_in[1];
    const float* W   = (const float*)d_in[2];
    const float* b   = (const float*)d_in[3];
    float* out = (float*)d_out;
    const int n_out = out_size;                       // 80000

    const size_t embt_bytes = (size_t)NSLICE * VOCAB * SDIM * sizeof(ushort); // 12.87 MB
    const size_t part_bytes = (size_t)NSLICE * n_out * sizeof(float);         // 1.28 MB

    if (ws_size < embt_bytes + part_bytes) {
        const int blocks = (n_out + 3) / 4;
        gelu_embed_fallback<<<blocks, 256, 0, stream>>>(x, emb, W, b, out, n_out);
        return;
    }

    ushort* embt = (ushort*)d_ws;
    float*  part = (float*)((char*)d_ws + embt_bytes);

    // 1) convert table to bf16, dim-sliced layout
    {
        const int nwork  = VOCAB * (DIM / 8);
        const int blocks = (nwork + 255) / 256;
        convert_kernel<<<blocks, 256, 0, stream>>>(emb, embt);
    }
    // 2) sliced gather + gelu + partial dot
    {
        const int nchunk = (n_out + 63) / 64;         // 64 outputs per block
        gather_kernel<<<NSLICE * nchunk, 256, 0, stream>>>(x, embt, W, part, n_out);
    }
    // 3) reduce partials + bias
    {
        const int blocks = (n_out + 255) / 256;
        reduce_kernel<<<blocks, 256, 0, stream>>>(part, b, out, n_out);
    }
}